// Round 1
// baseline (4141.811 us; speedup 1.0000x reference)
//
#include <hip/hip_runtime.h>
#include <math.h>

#define TS   128
#define BSZ  256
#define NI_  1024
#define NH_  2048
#define NO_  256
#define MROWS (TS * BSZ)   // 32768

#define BM 128
#define BN 64
#define BK 32

__device__ __forceinline__ float sigm(float v) { return 1.0f / (1.0f + expf(-v)); }

// ---------------------------------------------------------------------------
// Kernel 1: fused dual GEMM + activations.
//   out_c[m,n] = sigmoid( x[m,:]·W1[n,:] + b1[n] )   (cand   -> spk1 slot)
//   out_f[m,n] = relu   ( x[m,:]·Wr[n,:] + br[n] )   (forget -> mem1 slot)
// A row-major [M,K], W row-major [N,K] (i.e. NT GEMM). M=32768,N=2048,K=1024.
// Transposed LDS tiles (k-major) with +4 pad: 16B-aligned ds_read_b128,
// <=2-way bank aliasing (free on CDNA4).
// ---------------------------------------------------------------------------
__global__ __launch_bounds__(256, 4) void dual_gemm_act(
    const float* __restrict__ x,
    const float* __restrict__ W1, const float* __restrict__ b1,
    const float* __restrict__ Wr, const float* __restrict__ br,
    float* __restrict__ out_c, float* __restrict__ out_f)
{
    __shared__ float As [BK][BM + 4];
    __shared__ float B1s[BK][BN + 4];
    __shared__ float Brs[BK][BN + 4];

    const int tid = threadIdx.x;
    const int tx  = tid & 15;   // n group: 4 cols
    const int ty  = tid >> 4;   // m group: 8 rows
    const int n0  = blockIdx.x * BN;
    const int m0  = blockIdx.y * BM;

    float acc1[8][4], accr[8][4];
    #pragma unroll
    for (int i = 0; i < 8; ++i)
        #pragma unroll
        for (int j = 0; j < 4; ++j) { acc1[i][j] = 0.f; accr[i][j] = 0.f; }

    for (int k0 = 0; k0 < NI_; k0 += BK) {
        // stage A tile: BM x BK = 4096 floats, 4 float4 per thread, transposed
        #pragma unroll
        for (int r = 0; r < 4; ++r) {
            int s = r * 256 + tid;
            int row = s >> 3, kq = s & 7;
            float4 v = *reinterpret_cast<const float4*>(
                x + (size_t)(m0 + row) * NI_ + k0 + kq * 4);
            As[kq*4+0][row] = v.x; As[kq*4+1][row] = v.y;
            As[kq*4+2][row] = v.z; As[kq*4+3][row] = v.w;
        }
        // stage W1/Wr tiles: BN x BK = 2048 floats each, 2 float4 per thread
        #pragma unroll
        for (int r = 0; r < 2; ++r) {
            int s = r * 256 + tid;
            int row = s >> 3, kq = s & 7;
            float4 v = *reinterpret_cast<const float4*>(
                W1 + (size_t)(n0 + row) * NI_ + k0 + kq * 4);
            B1s[kq*4+0][row] = v.x; B1s[kq*4+1][row] = v.y;
            B1s[kq*4+2][row] = v.z; B1s[kq*4+3][row] = v.w;
            float4 w = *reinterpret_cast<const float4*>(
                Wr + (size_t)(n0 + row) * NI_ + k0 + kq * 4);
            Brs[kq*4+0][row] = w.x; Brs[kq*4+1][row] = w.y;
            Brs[kq*4+2][row] = w.z; Brs[kq*4+3][row] = w.w;
        }
        __syncthreads();

        #pragma unroll 8
        for (int kk = 0; kk < BK; ++kk) {
            float4 a0 = *reinterpret_cast<const float4*>(&As [kk][ty * 8]);
            float4 a1 = *reinterpret_cast<const float4*>(&As [kk][ty * 8 + 4]);
            float4 bb = *reinterpret_cast<const float4*>(&B1s[kk][tx * 4]);
            float4 rr = *reinterpret_cast<const float4*>(&Brs[kk][tx * 4]);
            float a[8]  = {a0.x, a0.y, a0.z, a0.w, a1.x, a1.y, a1.z, a1.w};
            float bv[4] = {bb.x, bb.y, bb.z, bb.w};
            float rv[4] = {rr.x, rr.y, rr.z, rr.w};
            #pragma unroll
            for (int i = 0; i < 8; ++i)
                #pragma unroll
                for (int j = 0; j < 4; ++j) {
                    acc1[i][j] = fmaf(a[i], bv[j], acc1[i][j]);
                    accr[i][j] = fmaf(a[i], rv[j], accr[i][j]);
                }
        }
        __syncthreads();
    }

    float bb1[4], bbr[4];
    #pragma unroll
    for (int j = 0; j < 4; ++j) {
        bb1[j] = b1[n0 + tx * 4 + j];
        bbr[j] = br[n0 + tx * 4 + j];
    }
    #pragma unroll
    for (int i = 0; i < 8; ++i) {
        size_t m = (size_t)m0 + ty * 8 + i;
        float4 cv, fv;
        cv.x = sigm(acc1[i][0] + bb1[0]);
        cv.y = sigm(acc1[i][1] + bb1[1]);
        cv.z = sigm(acc1[i][2] + bb1[2]);
        cv.w = sigm(acc1[i][3] + bb1[3]);
        fv.x = fmaxf(accr[i][0] + bbr[0], 0.f);
        fv.y = fmaxf(accr[i][1] + bbr[1], 0.f);
        fv.z = fmaxf(accr[i][2] + bbr[2], 0.f);
        fv.w = fmaxf(accr[i][3] + bbr[3], 0.f);
        *reinterpret_cast<float4*>(out_c + m * NH_ + n0 + tx * 4) = cv;
        *reinterpret_cast<float4*>(out_f + m * NH_ + n0 + tx * 4) = fv;
    }
}

// ---------------------------------------------------------------------------
// Kernel 2: hidden-layer scan. Elementwise over (b,h); serial over t.
// Reads cand (spk1 slot) / forget (mem1 slot), overwrites with spk1 / mem1.
//   syn = f*syn + (1-f)*c ; spk = (mem_old - 1 > 0) ; mem = 0.5*mem + syn - spk
// ---------------------------------------------------------------------------
__global__ __launch_bounds__(256) void hidden_scan(
    float4* __restrict__ cbuf, float4* __restrict__ fbuf)
{
    const int i = blockIdx.x * 256 + threadIdx.x;        // [0, B*NH/4)
    const int stride = BSZ * NH_ / 4;                    // 131072
    float s0=0.f,s1=0.f,s2=0.f,s3=0.f, m0v=0.f,m1v=0.f,m2v=0.f,m3v=0.f;
    for (int t = 0; t < TS; ++t) {
        size_t off = (size_t)t * stride + i;
        float4 c = cbuf[off];
        float4 f = fbuf[off];
        s0 = f.x*s0 + (1.f-f.x)*c.x;
        s1 = f.y*s1 + (1.f-f.y)*c.y;
        s2 = f.z*s2 + (1.f-f.z)*c.z;
        s3 = f.w*s3 + (1.f-f.w)*c.w;
        float k0 = (m0v - 1.f > 0.f) ? 1.f : 0.f;
        float k1 = (m1v - 1.f > 0.f) ? 1.f : 0.f;
        float k2 = (m2v - 1.f > 0.f) ? 1.f : 0.f;
        float k3 = (m3v - 1.f > 0.f) ? 1.f : 0.f;
        m0v = 0.5f*m0v + s0 - k0;
        m1v = 0.5f*m1v + s1 - k1;
        m2v = 0.5f*m2v + s2 - k2;
        m3v = 0.5f*m3v + s3 - k3;
        cbuf[off] = make_float4(k0, k1, k2, k3);
        fbuf[off] = make_float4(m0v, m1v, m2v, m3v);
    }
}

// ---------------------------------------------------------------------------
// Kernel 3: output GEMM. inp2[m,o] = spk1[m,:]·W2[o,:] + b2[o] -> spk2 slot.
// M=32768, N=256, K=2048.
// ---------------------------------------------------------------------------
__global__ __launch_bounds__(256, 4) void gemm_out(
    const float* __restrict__ A, const float* __restrict__ W2,
    const float* __restrict__ b2, float* __restrict__ out)
{
    __shared__ float As[BK][BM + 4];
    __shared__ float Bs[BK][BN + 4];

    const int tid = threadIdx.x;
    const int tx  = tid & 15;
    const int ty  = tid >> 4;
    const int n0  = blockIdx.x * BN;
    const int m0  = blockIdx.y * BM;

    float acc[8][4];
    #pragma unroll
    for (int i = 0; i < 8; ++i)
        #pragma unroll
        for (int j = 0; j < 4; ++j) acc[i][j] = 0.f;

    for (int k0 = 0; k0 < NH_; k0 += BK) {
        #pragma unroll
        for (int r = 0; r < 4; ++r) {
            int s = r * 256 + tid;
            int row = s >> 3, kq = s & 7;
            float4 v = *reinterpret_cast<const float4*>(
                A + (size_t)(m0 + row) * NH_ + k0 + kq * 4);
            As[kq*4+0][row] = v.x; As[kq*4+1][row] = v.y;
            As[kq*4+2][row] = v.z; As[kq*4+3][row] = v.w;
        }
        #pragma unroll
        for (int r = 0; r < 2; ++r) {
            int s = r * 256 + tid;
            int row = s >> 3, kq = s & 7;
            float4 v = *reinterpret_cast<const float4*>(
                W2 + (size_t)(n0 + row) * NH_ + k0 + kq * 4);
            Bs[kq*4+0][row] = v.x; Bs[kq*4+1][row] = v.y;
            Bs[kq*4+2][row] = v.z; Bs[kq*4+3][row] = v.w;
        }
        __syncthreads();

        #pragma unroll 8
        for (int kk = 0; kk < BK; ++kk) {
            float4 a0 = *reinterpret_cast<const float4*>(&As[kk][ty * 8]);
            float4 a1 = *reinterpret_cast<const float4*>(&As[kk][ty * 8 + 4]);
            float4 bb = *reinterpret_cast<const float4*>(&Bs[kk][tx * 4]);
            float a[8]  = {a0.x, a0.y, a0.z, a0.w, a1.x, a1.y, a1.z, a1.w};
            float bv[4] = {bb.x, bb.y, bb.z, bb.w};
            #pragma unroll
            for (int i = 0; i < 8; ++i)
                #pragma unroll
                for (int j = 0; j < 4; ++j)
                    acc[i][j] = fmaf(a[i], bv[j], acc[i][j]);
        }
        __syncthreads();
    }

    float bb2[4];
    #pragma unroll
    for (int j = 0; j < 4; ++j) bb2[j] = b2[n0 + tx * 4 + j];
    #pragma unroll
    for (int i = 0; i < 8; ++i) {
        size_t m = (size_t)m0 + ty * 8 + i;
        float4 ov;
        ov.x = acc[i][0] + bb2[0];
        ov.y = acc[i][1] + bb2[1];
        ov.z = acc[i][2] + bb2[2];
        ov.w = acc[i][3] + bb2[3];
        *reinterpret_cast<float4*>(out + m * NO_ + n0 + tx * 4) = ov;
    }
}

// ---------------------------------------------------------------------------
// Kernel 4: output-layer scan. Reads inp2 (spk2 slot), overwrites with spk2,
// writes mem2.  spk = (mem_old-1>0); syn = 0.5*syn + inp; mem = 0.5*mem+syn-spk
// ---------------------------------------------------------------------------
__global__ __launch_bounds__(256) void out_scan(
    float4* __restrict__ sbuf, float4* __restrict__ mbuf)
{
    const int i = blockIdx.x * 256 + threadIdx.x;        // [0, B*NO/4)
    const int stride = BSZ * NO_ / 4;                    // 16384
    float s0=0.f,s1=0.f,s2=0.f,s3=0.f, m0v=0.f,m1v=0.f,m2v=0.f,m3v=0.f;
    for (int t = 0; t < TS; ++t) {
        size_t off = (size_t)t * stride + i;
        float4 inp = sbuf[off];
        float k0 = (m0v - 1.f > 0.f) ? 1.f : 0.f;
        float k1 = (m1v - 1.f > 0.f) ? 1.f : 0.f;
        float k2 = (m2v - 1.f > 0.f) ? 1.f : 0.f;
        float k3 = (m3v - 1.f > 0.f) ? 1.f : 0.f;
        s0 = 0.5f*s0 + inp.x;
        s1 = 0.5f*s1 + inp.y;
        s2 = 0.5f*s2 + inp.z;
        s3 = 0.5f*s3 + inp.w;
        m0v = 0.5f*m0v + s0 - k0;
        m1v = 0.5f*m1v + s1 - k1;
        m2v = 0.5f*m2v + s2 - k2;
        m3v = 0.5f*m3v + s3 - k3;
        sbuf[off] = make_float4(k0, k1, k2, k3);
        mbuf[off] = make_float4(m0v, m1v, m2v, m3v);
    }
}

extern "C" void kernel_launch(void* const* d_in, const int* in_sizes, int n_in,
                              void* d_out, int out_size, void* d_ws, size_t ws_size,
                              hipStream_t stream) {
    const float* x  = (const float*)d_in[0];
    const float* W1 = (const float*)d_in[1];
    const float* b1 = (const float*)d_in[2];
    const float* Wr = (const float*)d_in[3];
    const float* br = (const float*)d_in[4];
    const float* W2 = (const float*)d_in[5];
    const float* b2 = (const float*)d_in[6];

    float* out = (float*)d_out;
    float* o_spk1 = out;                                  // [T,B,NH]
    float* o_mem1 = out + (size_t)TS * BSZ * NH_;         // [T,B,NH]
    float* o_spk2 = o_mem1 + (size_t)TS * BSZ * NH_;      // [T,B,NO]
    float* o_mem2 = o_spk2 + (size_t)TS * BSZ * NO_;      // [T,B,NO]

    // 1) cand -> spk1 slot, forget -> mem1 slot
    dim3 gA(NH_ / BN, MROWS / BM);            // (32, 256)
    dual_gemm_act<<<gA, 256, 0, stream>>>(x, W1, b1, Wr, br, o_spk1, o_mem1);

    // 2) elementwise hidden scan over t (read cand/forget, write spk1/mem1)
    hidden_scan<<<(BSZ * NH_ / 4) / 256, 256, 0, stream>>>(
        (float4*)o_spk1, (float4*)o_mem1);

    // 3) inp2 = spk1 @ W2^T + b2 -> spk2 slot
    dim3 gC(NO_ / BN, MROWS / BM);            // (4, 256)
    gemm_out<<<gC, 256, 0, stream>>>(o_spk1, W2, b2, o_spk2);

    // 4) elementwise output scan (read inp2, write spk2/mem2)
    out_scan<<<(BSZ * NO_ / 4) / 256, 256, 0, stream>>>(
        (float4*)o_spk2, (float4*)o_mem2);
}

// Round 3
// 1897.901 us; speedup vs baseline: 2.1823x; 2.1823x over previous
//
#include <hip/hip_runtime.h>
#include <math.h>

#define TS   128
#define BSZ  256
#define NI_  1024
#define NH_  2048
#define NO_  256
#define MROWS (TS * BSZ)   // 32768

typedef __attribute__((ext_vector_type(8))) short short8_t;  // 8 bf16 = 4 VGPR
typedef __attribute__((ext_vector_type(4))) short short4_t;  // 8 B
typedef __attribute__((ext_vector_type(4))) float f32x4;     // MFMA acc

#define LDK 40   // LDS row stride in shorts: 32 data + 8 pad = 80 B (16B-aligned rows)

// fp32 -> (bf16 hi, bf16 lo) split. hi = RNE(f); lo = RNE(f - hi).
__device__ __forceinline__ void cvt_hl(float f, short& h, short& l) {
    __bf16 hb = (__bf16)f;
    float  hf = (float)hb;
    __bf16 lb = (__bf16)(f - hf);
    h = __builtin_bit_cast(short, hb);
    l = __builtin_bit_cast(short, lb);
}

// ---------------------------------------------------------------------------
// Kernel 1: split-3 bf16 MFMA GEMM, concat-N over [W1; Wr], fused activation.
// C[m, n] = act( x[m,:] . W[n,:] + b[n] ),  M=32768, N'=4096, K=1024.
// blockIdx.x < 16 -> W1/sigmoid -> out_c ; >= 16 -> Wr/relu -> out_f.
// 128x128 tile, BK=32, 4 waves (64x64 each), 16x16x32 bf16 MFMA.
// ---------------------------------------------------------------------------
__global__ __launch_bounds__(256) void gemm1_mfma(
    const float* __restrict__ x,
    const float* __restrict__ W1, const float* __restrict__ b1,
    const float* __restrict__ Wr, const float* __restrict__ br,
    float* __restrict__ out_c, float* __restrict__ out_f)
{
    __shared__ __align__(16) short Ah[128 * LDK];
    __shared__ __align__(16) short Al[128 * LDK];
    __shared__ __align__(16) short Bh[128 * LDK];
    __shared__ __align__(16) short Bl[128 * LDK];

    const int tid = threadIdx.x;
    const int bx  = blockIdx.x;
    const int m0  = blockIdx.y * 128;

    const float* Wp; const float* bp; float* outp; int n0; bool is_sig;
    if (bx < 16) { Wp = W1; bp = b1; outp = out_c; n0 = bx * 128;        is_sig = true;  }
    else         { Wp = Wr; bp = br; outp = out_f; n0 = (bx - 16) * 128; is_sig = false; }

    const int srow = tid >> 3;   // 0..31
    const int skq  = tid & 7;    // k-quad 0..7

    const float* aptr = x  + (size_t)(m0 + srow) * NI_ + skq * 4;
    const float* wptr = Wp + (size_t)(n0 + srow) * NI_ + skq * 4;

    const int lane = tid & 63;
    const int wid  = tid >> 6;
    const int wm   = (wid >> 1) * 64;   // wave m-offset
    const int wn   = (wid & 1)  * 64;   // wave n-offset
    const int fr   = lane & 15;         // row/col within fragment
    const int fg   = lane >> 4;         // k-chunk group 0..3

    f32x4 acc[4][4];
    #pragma unroll
    for (int i = 0; i < 4; ++i)
        #pragma unroll
        for (int j = 0; j < 4; ++j) acc[i][j] = f32x4{0.f, 0.f, 0.f, 0.f};

    for (int k0 = 0; k0 < NI_; k0 += 32) {
        // ---- stage: load fp32, split to bf16 hi/lo, write LDS ----
        #pragma unroll
        for (int r = 0; r < 4; ++r) {
            int row = r * 32 + srow;
            float4 va = *reinterpret_cast<const float4*>(aptr + (size_t)r * 32 * NI_ + k0);
            float4 vw = *reinterpret_cast<const float4*>(wptr + (size_t)r * 32 * NI_ + k0);
            short h0,h1,h2,h3,l0,l1,l2,l3;
            cvt_hl(va.x,h0,l0); cvt_hl(va.y,h1,l1); cvt_hl(va.z,h2,l2); cvt_hl(va.w,h3,l3);
            *reinterpret_cast<short4_t*>(&Ah[row * LDK + skq * 4]) = short4_t{h0,h1,h2,h3};
            *reinterpret_cast<short4_t*>(&Al[row * LDK + skq * 4]) = short4_t{l0,l1,l2,l3};
            cvt_hl(vw.x,h0,l0); cvt_hl(vw.y,h1,l1); cvt_hl(vw.z,h2,l2); cvt_hl(vw.w,h3,l3);
            *reinterpret_cast<short4_t*>(&Bh[row * LDK + skq * 4]) = short4_t{h0,h1,h2,h3};
            *reinterpret_cast<short4_t*>(&Bl[row * LDK + skq * 4]) = short4_t{l0,l1,l2,l3};
        }
        __syncthreads();

        // ---- compute: 48 MFMAs per wave per k-step ----
        short8_t bh[4], bl[4];
        #pragma unroll
        for (int nf = 0; nf < 4; ++nf) {
            int nrow = wn + nf * 16 + fr;
            bh[nf] = *reinterpret_cast<const short8_t*>(&Bh[nrow * LDK + fg * 8]);
            bl[nf] = *reinterpret_cast<const short8_t*>(&Bl[nrow * LDK + fg * 8]);
        }
        #pragma unroll
        for (int mf = 0; mf < 4; ++mf) {
            int arow = wm + mf * 16 + fr;
            short8_t ah = *reinterpret_cast<const short8_t*>(&Ah[arow * LDK + fg * 8]);
            short8_t al = *reinterpret_cast<const short8_t*>(&Al[arow * LDK + fg * 8]);
            #pragma unroll
            for (int nf = 0; nf < 4; ++nf) {
                acc[mf][nf] = __builtin_amdgcn_mfma_f32_16x16x32_bf16(ah, bh[nf], acc[mf][nf], 0, 0, 0);
                acc[mf][nf] = __builtin_amdgcn_mfma_f32_16x16x32_bf16(ah, bl[nf], acc[mf][nf], 0, 0, 0);
                acc[mf][nf] = __builtin_amdgcn_mfma_f32_16x16x32_bf16(al, bh[nf], acc[mf][nf], 0, 0, 0);
            }
        }
        __syncthreads();
    }

    // ---- epilogue: bias + activation, scalar stores (col=lane&15, row=(lane>>4)*4+j) ----
    if (is_sig) {
        #pragma unroll
        for (int nf = 0; nf < 4; ++nf) {
            int col = n0 + wn + nf * 16 + fr;
            float bias = bp[col];
            #pragma unroll
            for (int mf = 0; mf < 4; ++mf) {
                int rbase = m0 + wm + mf * 16 + fg * 4;
                f32x4 a = acc[mf][nf];
                #pragma unroll
                for (int j = 0; j < 4; ++j) {
                    float v = a[j] + bias;
                    outp[(size_t)(rbase + j) * NH_ + col] = 1.f / (1.f + __expf(-v));
                }
            }
        }
    } else {
        #pragma unroll
        for (int nf = 0; nf < 4; ++nf) {
            int col = n0 + wn + nf * 16 + fr;
            float bias = bp[col];
            #pragma unroll
            for (int mf = 0; mf < 4; ++mf) {
                int rbase = m0 + wm + mf * 16 + fg * 4;
                f32x4 a = acc[mf][nf];
                #pragma unroll
                for (int j = 0; j < 4; ++j) {
                    float v = a[j] + bias;
                    outp[(size_t)(rbase + j) * NH_ + col] = fmaxf(v, 0.f);
                }
            }
        }
    }
}

// ---------------------------------------------------------------------------
// Kernel 2: hidden-layer scan (unchanged). Overwrites cand/forget with spk1/mem1.
// ---------------------------------------------------------------------------
__global__ __launch_bounds__(256) void hidden_scan(
    float4* __restrict__ cbuf, float4* __restrict__ fbuf)
{
    const int i = blockIdx.x * 256 + threadIdx.x;        // [0, B*NH/4)
    const int stride = BSZ * NH_ / 4;                    // 131072
    float s0=0.f,s1=0.f,s2=0.f,s3=0.f, m0v=0.f,m1v=0.f,m2v=0.f,m3v=0.f;
    for (int t = 0; t < TS; ++t) {
        size_t off = (size_t)t * stride + i;
        float4 c = cbuf[off];
        float4 f = fbuf[off];
        s0 = f.x*s0 + (1.f-f.x)*c.x;
        s1 = f.y*s1 + (1.f-f.y)*c.y;
        s2 = f.z*s2 + (1.f-f.z)*c.z;
        s3 = f.w*s3 + (1.f-f.w)*c.w;
        float k0 = (m0v - 1.f > 0.f) ? 1.f : 0.f;
        float k1 = (m1v - 1.f > 0.f) ? 1.f : 0.f;
        float k2 = (m2v - 1.f > 0.f) ? 1.f : 0.f;
        float k3 = (m3v - 1.f > 0.f) ? 1.f : 0.f;
        m0v = 0.5f*m0v + s0 - k0;
        m1v = 0.5f*m1v + s1 - k1;
        m2v = 0.5f*m2v + s2 - k2;
        m3v = 0.5f*m3v + s3 - k3;
        cbuf[off] = make_float4(k0, k1, k2, k3);
        fbuf[off] = make_float4(m0v, m1v, m2v, m3v);
    }
}

// ---------------------------------------------------------------------------
// Kernel 3: split-2 bf16 MFMA GEMM (spk1 is exactly representable in bf16).
// inp2[m,o] = spk1[m,:] . W2[o,:] + b2[o].  M=32768, N=256, K=2048.
// ---------------------------------------------------------------------------
__global__ __launch_bounds__(256) void gemm2_mfma(
    const float* __restrict__ A, const float* __restrict__ W2,
    const float* __restrict__ b2, float* __restrict__ out)
{
    __shared__ __align__(16) short Ah[128 * LDK];
    __shared__ __align__(16) short Bh[128 * LDK];
    __shared__ __align__(16) short Bl[128 * LDK];

    const int tid = threadIdx.x;
    const int n0  = blockIdx.x * 128;
    const int m0  = blockIdx.y * 128;

    const int srow = tid >> 3;
    const int skq  = tid & 7;

    const float* aptr = A  + (size_t)(m0 + srow) * NH_ + skq * 4;
    const float* wptr = W2 + (size_t)(n0 + srow) * NH_ + skq * 4;

    const int lane = tid & 63;
    const int wid  = tid >> 6;
    const int wm   = (wid >> 1) * 64;
    const int wn   = (wid & 1)  * 64;
    const int fr   = lane & 15;
    const int fg   = lane >> 4;

    f32x4 acc[4][4];
    #pragma unroll
    for (int i = 0; i < 4; ++i)
        #pragma unroll
        for (int j = 0; j < 4; ++j) acc[i][j] = f32x4{0.f, 0.f, 0.f, 0.f};

    for (int k0 = 0; k0 < NH_; k0 += 32) {
        #pragma unroll
        for (int r = 0; r < 4; ++r) {
            int row = r * 32 + srow;
            float4 va = *reinterpret_cast<const float4*>(aptr + (size_t)r * 32 * NH_ + k0);
            float4 vw = *reinterpret_cast<const float4*>(wptr + (size_t)r * 32 * NH_ + k0);
            // spk1 in {0,1}: bf16-exact, no lo term
            short a0 = __builtin_bit_cast(short, (__bf16)va.x);
            short a1 = __builtin_bit_cast(short, (__bf16)va.y);
            short a2 = __builtin_bit_cast(short, (__bf16)va.z);
            short a3 = __builtin_bit_cast(short, (__bf16)va.w);
            *reinterpret_cast<short4_t*>(&Ah[row * LDK + skq * 4]) = short4_t{a0,a1,a2,a3};
            short h0,h1,h2,h3,l0,l1,l2,l3;
            cvt_hl(vw.x,h0,l0); cvt_hl(vw.y,h1,l1); cvt_hl(vw.z,h2,l2); cvt_hl(vw.w,h3,l3);
            *reinterpret_cast<short4_t*>(&Bh[row * LDK + skq * 4]) = short4_t{h0,h1,h2,h3};
            *reinterpret_cast<short4_t*>(&Bl[row * LDK + skq * 4]) = short4_t{l0,l1,l2,l3};
        }
        __syncthreads();

        short8_t bh[4], bl[4];
        #pragma unroll
        for (int nf = 0; nf < 4; ++nf) {
            int nrow = wn + nf * 16 + fr;
            bh[nf] = *reinterpret_cast<const short8_t*>(&Bh[nrow * LDK + fg * 8]);
            bl[nf] = *reinterpret_cast<const short8_t*>(&Bl[nrow * LDK + fg * 8]);
        }
        #pragma unroll
        for (int mf = 0; mf < 4; ++mf) {
            int arow = wm + mf * 16 + fr;
            short8_t ah = *reinterpret_cast<const short8_t*>(&Ah[arow * LDK + fg * 8]);
            #pragma unroll
            for (int nf = 0; nf < 4; ++nf) {
                acc[mf][nf] = __builtin_amdgcn_mfma_f32_16x16x32_bf16(ah, bh[nf], acc[mf][nf], 0, 0, 0);
                acc[mf][nf] = __builtin_amdgcn_mfma_f32_16x16x32_bf16(ah, bl[nf], acc[mf][nf], 0, 0, 0);
            }
        }
        __syncthreads();
    }

    #pragma unroll
    for (int nf = 0; nf < 4; ++nf) {
        int col = n0 + wn + nf * 16 + fr;
        float bias = b2[col];
        #pragma unroll
        for (int mf = 0; mf < 4; ++mf) {
            int rbase = m0 + wm + mf * 16 + fg * 4;
            f32x4 a = acc[mf][nf];
            #pragma unroll
            for (int j = 0; j < 4; ++j)
                out[(size_t)(rbase + j) * NO_ + col] = a[j] + bias;
        }
    }
}

// ---------------------------------------------------------------------------
// Kernel 4: output-layer scan (unchanged).
// ---------------------------------------------------------------------------
__global__ __launch_bounds__(256) void out_scan(
    float4* __restrict__ sbuf, float4* __restrict__ mbuf)
{
    const int i = blockIdx.x * 256 + threadIdx.x;        // [0, B*NO/4)
    const int stride = BSZ * NO_ / 4;                    // 16384
    float s0=0.f,s1=0.f,s2=0.f,s3=0.f, m0v=0.f,m1v=0.f,m2v=0.f,m3v=0.f;
    for (int t = 0; t < TS; ++t) {
        size_t off = (size_t)t * stride + i;
        float4 inp = sbuf[off];
        float k0 = (m0v - 1.f > 0.f) ? 1.f : 0.f;
        float k1 = (m1v - 1.f > 0.f) ? 1.f : 0.f;
        float k2 = (m2v - 1.f > 0.f) ? 1.f : 0.f;
        float k3 = (m3v - 1.f > 0.f) ? 1.f : 0.f;
        s0 = 0.5f*s0 + inp.x;
        s1 = 0.5f*s1 + inp.y;
        s2 = 0.5f*s2 + inp.z;
        s3 = 0.5f*s3 + inp.w;
        m0v = 0.5f*m0v + s0 - k0;
        m1v = 0.5f*m1v + s1 - k1;
        m2v = 0.5f*m2v + s2 - k2;
        m3v = 0.5f*m3v + s3 - k3;
        sbuf[off] = make_float4(k0, k1, k2, k3);
        mbuf[off] = make_float4(m0v, m1v, m2v, m3v);
    }
}

extern "C" void kernel_launch(void* const* d_in, const int* in_sizes, int n_in,
                              void* d_out, int out_size, void* d_ws, size_t ws_size,
                              hipStream_t stream) {
    const float* x  = (const float*)d_in[0];
    const float* W1 = (const float*)d_in[1];
    const float* b1 = (const float*)d_in[2];
    const float* Wr = (const float*)d_in[3];
    const float* br = (const float*)d_in[4];
    const float* W2 = (const float*)d_in[5];
    const float* b2 = (const float*)d_in[6];

    float* out = (float*)d_out;
    float* o_spk1 = out;                                  // [T,B,NH]
    float* o_mem1 = out + (size_t)TS * BSZ * NH_;         // [T,B,NH]
    float* o_spk2 = o_mem1 + (size_t)TS * BSZ * NH_;      // [T,B,NO]
    float* o_mem2 = o_spk2 + (size_t)TS * BSZ * NO_;      // [T,B,NO]

    // 1) cand -> spk1 slot (sigmoid), forget -> mem1 slot (relu), MFMA split-3
    dim3 g1(32, MROWS / 128);                 // (32, 256)
    gemm1_mfma<<<g1, 256, 0, stream>>>(x, W1, b1, Wr, br, o_spk1, o_mem1);

    // 2) elementwise hidden scan over t
    hidden_scan<<<(BSZ * NH_ / 4) / 256, 256, 0, stream>>>(
        (float4*)o_spk1, (float4*)o_mem1);

    // 3) inp2 = spk1 @ W2^T + b2 -> spk2 slot, MFMA split-2
    dim3 g2(NO_ / 128, MROWS / 128);          // (2, 256)
    gemm2_mfma<<<g2, 256, 0, stream>>>(o_spk1, W2, b2, o_spk2);

    // 4) elementwise output scan
    out_scan<<<(BSZ * NO_ / 4) / 256, 256, 0, stream>>>(
        (float4*)o_spk2, (float4*)o_mem2);
}